// Round 1
// baseline (2434.708 us; speedup 1.0000x reference)
//
#include <hip/hip_runtime.h>
#include <cstddef>

constexpr int V_CNT = 65536;
constexpr int H_DIM = 128;
constexpr int CI = 34;   // chem in
constexpr int GI = 48;   // geom in
#define EPSF 1e-5f

__device__ __forceinline__ float sigmoidf_(float x){ return 1.0f/(1.0f+__expf(-x)); }
__device__ __forceinline__ float siluf_(float x){ return x/(1.0f+__expf(-x)); }
__device__ __forceinline__ float softplusf_(float x){
  return fmaxf(x,0.0f) + __logf(1.0f + __expf(-fabsf(x)));
}
__device__ __forceinline__ void fma4(float4& a, float s, float4 w){
  a.x = fmaf(s,w.x,a.x); a.y = fmaf(s,w.y,a.y);
  a.z = fmaf(s,w.z,a.z); a.w = fmaf(s,w.w,a.w);
}

__global__ __launch_bounds__(256) void zero_f4(float4* p, int n4){
  int i = blockIdx.x*blockDim.x + threadIdx.x;
  int stride = gridDim.x*blockDim.x;
  float4 z; z.x=0.f; z.y=0.f; z.z=0.f; z.w=0.f;
  for(; i<n4; i+=stride) p[i] = z;
}

// ---------------- geom MLP: [V,48] -> silu(bn(.@wg1+bg1)) -> bn(.@wg2+bg2) -> h_geom [V,64]
__global__ __launch_bounds__(256) void geom_kernel(
    const float* __restrict__ geom,
    const float* __restrict__ wg1, const float* __restrict__ bg1, const float* __restrict__ bng1,
    const float* __restrict__ wg2, const float* __restrict__ bg2, const float* __restrict__ bng2,
    float* __restrict__ h_geom)
{
  __shared__ float w1s[GI][64];
  __shared__ float w2s[64][64];
  __shared__ float sc1[64], sh1[64], sc2[64], sh2[64];
  const int t = threadIdx.x;
  for(int i=t;i<GI*64;i+=256) ((float*)w1s)[i] = wg1[i];
  for(int i=t;i<64*64;i+=256) ((float*)w2s)[i] = wg2[i];
  if(t<64){
    float g=bng1[t], b=bng1[64+t], m=bng1[128+t], vv=bng1[192+t];
    float s=g*rsqrtf(vv+EPSF); sc1[t]=s; sh1[t]=fmaf(s, bg1[t]-m, b);
  } else if(t<128){
    int c=t-64;
    float g=bng2[c], b=bng2[64+c], m=bng2[128+c], vv=bng2[192+c];
    float s=g*rsqrtf(vv+EPSF); sc2[c]=s; sh2[c]=fmaf(s, bg2[c]-m, b);
  }
  __syncthreads();

  const int vtx = blockIdx.x*256 + t;
  float x[GI];
  const float4* xr = (const float4*)(geom + (size_t)vtx*GI);
  #pragma unroll
  for(int i=0;i<GI/4;i++){ float4 q=xr[i]; x[4*i]=q.x; x[4*i+1]=q.y; x[4*i+2]=q.z; x[4*i+3]=q.w; }

  float4 a1[16];
  #pragma unroll
  for(int q=0;q<16;q++){ a1[q].x=0.f; a1[q].y=0.f; a1[q].z=0.f; a1[q].w=0.f; }
  for(int k=0;k<GI;k++){
    float xv = x[k];
    const float4* wr = (const float4*)&w1s[k][0];
    #pragma unroll
    for(int q=0;q<16;q++) fma4(a1[q], xv, wr[q]);
  }
  float g1[64];
  #pragma unroll
  for(int q=0;q<16;q++){
    int j=4*q;
    g1[j+0]=siluf_(fmaf(a1[q].x, sc1[j+0], sh1[j+0]));
    g1[j+1]=siluf_(fmaf(a1[q].y, sc1[j+1], sh1[j+1]));
    g1[j+2]=siluf_(fmaf(a1[q].z, sc1[j+2], sh1[j+2]));
    g1[j+3]=siluf_(fmaf(a1[q].w, sc1[j+3], sh1[j+3]));
  }
  float4 a2[16];
  #pragma unroll
  for(int q=0;q<16;q++){ a2[q].x=0.f; a2[q].y=0.f; a2[q].z=0.f; a2[q].w=0.f; }
  for(int k=0;k<64;k++){
    float gv = g1[k];
    const float4* wr = (const float4*)&w2s[k][0];
    #pragma unroll
    for(int q=0;q<16;q++) fma4(a2[q], gv, wr[q]);
  }
  float* dst = h_geom + (size_t)vtx*64;
  #pragma unroll
  for(int q=0;q<16;q++){
    int j=4*q;
    float4 o;
    o.x=fmaf(a2[q].x, sc2[j+0], sh2[j+0]);
    o.y=fmaf(a2[q].y, sc2[j+1], sh2[j+1]);
    o.z=fmaf(a2[q].z, sc2[j+2], sh2[j+2]);
    o.w=fmaf(a2[q].w, sc2[j+3], sh2[j+3]);
    *(float4*)(dst+j) = o;
  }
}

// ---------------- chem MLP + gated scatter-add
// 64 edges per block of 256 threads.
__global__ __launch_bounds__(256,2) void chem_kernel(
    const float* __restrict__ chem, const int* __restrict__ vids,
    const float* __restrict__ w1, const float* __restrict__ b1, const float* __restrict__ bn1,
    const float* __restrict__ w2, const float* __restrict__ b2, const float* __restrict__ bn2,
    float* __restrict__ h_chem)
{
  __shared__ float xs[64][36];      // padded 34->36
  __shared__ float w1s[CI][128];
  __shared__ float a1s[64][132];    // padded 128->132 (16B-aligned rows)
  __shared__ float sc1[128], sh1[128];
  __shared__ float sc2[256], sh2[256];
  __shared__ int   vid_s[64];

  const int t = threadIdx.x;
  const long e0 = (long)blockIdx.x * 64;

  for(int i=t;i<64*CI;i+=256){ int e=i/CI, k=i-e*CI; xs[e][k] = chem[e0*CI + i]; }
  for(int i=t;i<CI*128;i+=256) ((float*)w1s)[i] = w1[i];
  if(t<64) vid_s[t] = vids[e0+t];
  if(t<128){
    float g=bn1[t], b=bn1[128+t], m=bn1[256+t], vv=bn1[384+t];
    float s=g*rsqrtf(vv+EPSF); sc1[t]=s; sh1[t]=fmaf(s, b1[t]-m, b);
  }
  {
    float g=bn2[t], b=bn2[256+t], m=bn2[512+t], vv=bn2[768+t];
    float s=g*rsqrtf(vv+EPSF); sc2[t]=s; sh2[t]=fmaf(s, b2[t]-m, b);
  }
  __syncthreads();

  // ---- layer 1: 4 threads/edge, each does 32 of 128 hidden (j = 16q + 4*l4 + jj)
  {
    const int e = t>>2, l4 = t&3;
    float4 accA[8];
    #pragma unroll
    for(int q=0;q<8;q++){ accA[q].x=0.f; accA[q].y=0.f; accA[q].z=0.f; accA[q].w=0.f; }
    for(int k=0;k<CI;k++){
      float xv = xs[e][k];
      const float4* wr = (const float4*)&w1s[k][0];
      #pragma unroll
      for(int q=0;q<8;q++) fma4(accA[q], xv, wr[4*q + l4]);
    }
    #pragma unroll
    for(int q=0;q<8;q++){
      int j = 16*q + 4*l4;
      a1s[e][j+0] = siluf_(fmaf(accA[q].x, sc1[j+0], sh1[j+0]));
      a1s[e][j+1] = siluf_(fmaf(accA[q].y, sc1[j+1], sh1[j+1]));
      a1s[e][j+2] = siluf_(fmaf(accA[q].z, sc1[j+2], sh1[j+2]));
      a1s[e][j+3] = siluf_(fmaf(accA[q].w, sc1[j+3], sh1[j+3]));
    }
  }
  __syncthreads();

  // ---- layer 2: thread (eb,cb) does 8 edges x (4 filter cols + 4 core cols)
  {
    const int eb = t>>5, cb = t&31;
    const int cb4 = cb*4;
    float4 accF[8], accC[8];
    #pragma unroll
    for(int i=0;i<8;i++){
      accF[i].x=0.f; accF[i].y=0.f; accF[i].z=0.f; accF[i].w=0.f;
      accC[i].x=0.f; accC[i].y=0.f; accC[i].z=0.f; accC[i].w=0.f;
    }
    const float* w2f = w2 + cb4;         // filter cols [0,128)
    const float* w2c = w2 + 128 + cb4;   // core   cols [128,256)
    for(int k=0;k<H_DIM;k+=4){
      float4 wf0 = *(const float4*)(w2f + (size_t)(k+0)*256);
      float4 wf1_= *(const float4*)(w2f + (size_t)(k+1)*256);
      float4 wf2_= *(const float4*)(w2f + (size_t)(k+2)*256);
      float4 wf3_= *(const float4*)(w2f + (size_t)(k+3)*256);
      float4 wc0 = *(const float4*)(w2c + (size_t)(k+0)*256);
      float4 wc1 = *(const float4*)(w2c + (size_t)(k+1)*256);
      float4 wc2 = *(const float4*)(w2c + (size_t)(k+2)*256);
      float4 wc3 = *(const float4*)(w2c + (size_t)(k+3)*256);
      #pragma unroll
      for(int i=0;i<8;i++){
        float4 a = *(const float4*)&a1s[eb*8+i][k];
        fma4(accF[i], a.x, wf0); fma4(accF[i], a.y, wf1_);
        fma4(accF[i], a.z, wf2_); fma4(accF[i], a.w, wf3_);
        fma4(accC[i], a.x, wc0); fma4(accC[i], a.y, wc1);
        fma4(accC[i], a.z, wc2); fma4(accC[i], a.w, wc3);
      }
    }
    #pragma unroll
    for(int i=0;i<8;i++){
      int vtx = vid_s[eb*8+i];
      float* dst = h_chem + (size_t)vtx*H_DIM + cb4;
      float4 F = accF[i], C = accC[i];
      float f0 = fmaf(F.x, sc2[cb4+0], sh2[cb4+0]);
      float f1 = fmaf(F.y, sc2[cb4+1], sh2[cb4+1]);
      float f2 = fmaf(F.z, sc2[cb4+2], sh2[cb4+2]);
      float f3 = fmaf(F.w, sc2[cb4+3], sh2[cb4+3]);
      float c0 = fmaf(C.x, sc2[128+cb4+0], sh2[128+cb4+0]);
      float c1 = fmaf(C.y, sc2[128+cb4+1], sh2[128+cb4+1]);
      float c2 = fmaf(C.z, sc2[128+cb4+2], sh2[128+cb4+2]);
      float c3 = fmaf(C.w, sc2[128+cb4+3], sh2[128+cb4+3]);
      atomicAdd(dst+0, sigmoidf_(f0)*softplusf_(c0));
      atomicAdd(dst+1, sigmoidf_(f1)*softplusf_(c1));
      atomicAdd(dst+2, sigmoidf_(f2)*softplusf_(c2));
      atomicAdd(dst+3, sigmoidf_(f3)*softplusf_(c3));
    }
  }
}

// ---------------- feat MLP: concat(h_chem,h_geom) [V,192] -> silu(bn(.@wf1)) -> bn(.@wf2) -> out [V,128]
__global__ __launch_bounds__(256) void feat_kernel(
    const float* __restrict__ h_chem, const float* __restrict__ h_geom,
    const float* __restrict__ wf1, const float* __restrict__ bf1, const float* __restrict__ bnf1,
    const float* __restrict__ wf2, const float* __restrict__ bf2, const float* __restrict__ bnf2,
    float* __restrict__ out)
{
  __shared__ float xsF[32][196];   // padded 192->196
  __shared__ float y1s[32][132];   // padded 128->132
  __shared__ float s1[128], h1[128], s2[128], h2[128];
  const int t = threadIdx.x;
  const int v0 = blockIdx.x*32;

  for(int i=t;i<32*128;i+=256){ int v=i>>7, k=i&127; xsF[v][k]     = h_chem[(size_t)(v0+v)*128 + k]; }
  for(int i=t;i<32*64; i+=256){ int v=i>>6, k=i&63;  xsF[v][128+k] = h_geom[(size_t)(v0+v)*64  + k]; }
  if(t<128){
    float g=bnf1[t], b=bnf1[128+t], m=bnf1[256+t], vv=bnf1[384+t];
    float s=g*rsqrtf(vv+EPSF); s1[t]=s; h1[t]=fmaf(s, bf1[t]-m, b);
  } else {
    int c=t-128;
    float g=bnf2[c], b=bnf2[128+c], m=bnf2[256+c], vv=bnf2[384+c];
    float s=g*rsqrtf(vv+EPSF); s2[c]=s; h2[c]=fmaf(s, bf2[c]-m, b);
  }
  __syncthreads();

  const int v = t>>3, l8 = t&7;   // 8 threads per vertex; j = 32q + 4*l8 + jj
  float4 acc[4];
  #pragma unroll
  for(int q=0;q<4;q++){ acc[q].x=0.f; acc[q].y=0.f; acc[q].z=0.f; acc[q].w=0.f; }
  for(int k=0;k<192;k++){
    float xv = xsF[v][k];
    const float4* wr = (const float4*)(wf1 + (size_t)k*128);
    #pragma unroll
    for(int q=0;q<4;q++) fma4(acc[q], xv, wr[8*q + l8]);
  }
  #pragma unroll
  for(int q=0;q<4;q++){
    int j = 32*q + 4*l8;
    y1s[v][j+0] = siluf_(fmaf(acc[q].x, s1[j+0], h1[j+0]));
    y1s[v][j+1] = siluf_(fmaf(acc[q].y, s1[j+1], h1[j+1]));
    y1s[v][j+2] = siluf_(fmaf(acc[q].z, s1[j+2], h1[j+2]));
    y1s[v][j+3] = siluf_(fmaf(acc[q].w, s1[j+3], h1[j+3]));
  }
  __syncthreads();

  float4 acc2[4];
  #pragma unroll
  for(int q=0;q<4;q++){ acc2[q].x=0.f; acc2[q].y=0.f; acc2[q].z=0.f; acc2[q].w=0.f; }
  for(int k=0;k<128;k++){
    float yv = y1s[v][k];
    const float4* wr = (const float4*)(wf2 + (size_t)k*128);
    #pragma unroll
    for(int q=0;q<4;q++) fma4(acc2[q], yv, wr[8*q + l8]);
  }
  #pragma unroll
  for(int q=0;q<4;q++){
    int j = 32*q + 4*l8;
    float4 o;
    o.x=fmaf(acc2[q].x, s2[j+0], h2[j+0]);
    o.y=fmaf(acc2[q].y, s2[j+1], h2[j+1]);
    o.z=fmaf(acc2[q].z, s2[j+2], h2[j+2]);
    o.w=fmaf(acc2[q].w, s2[j+3], h2[j+3]);
    *(float4*)(out + (size_t)(v0+v)*128 + j) = o;
  }
}

extern "C" void kernel_launch(void* const* d_in, const int* in_sizes, int n_in,
                              void* d_out, int out_size, void* d_ws, size_t ws_size,
                              hipStream_t stream) {
  const float* chem = (const float*)d_in[0];
  const float* geom = (const float*)d_in[1];
  const int*   vids = (const int*)d_in[2];
  const float* w1  = (const float*)d_in[3];
  const float* b1  = (const float*)d_in[4];
  const float* bn1 = (const float*)d_in[5];
  const float* w2  = (const float*)d_in[6];
  const float* b2  = (const float*)d_in[7];
  const float* bn2 = (const float*)d_in[8];
  const float* wg1 = (const float*)d_in[9];
  const float* bg1 = (const float*)d_in[10];
  const float* bng1= (const float*)d_in[11];
  const float* wg2 = (const float*)d_in[12];
  const float* bg2 = (const float*)d_in[13];
  const float* bng2= (const float*)d_in[14];
  const float* wf1 = (const float*)d_in[15];
  const float* bf1 = (const float*)d_in[16];
  const float* bnf1= (const float*)d_in[17];
  const float* wf2 = (const float*)d_in[18];
  const float* bf2 = (const float*)d_in[19];
  const float* bnf2= (const float*)d_in[20];

  float* h_chem = (float*)d_ws;                       // [V,128] fp32 = 32 MB
  float* h_geom = h_chem + (size_t)V_CNT*H_DIM;       // [V, 64] fp32 = 16 MB
  float* out    = (float*)d_out;

  zero_f4<<<dim3(4096), dim3(256), 0, stream>>>((float4*)h_chem, V_CNT*H_DIM/4);
  geom_kernel<<<dim3(V_CNT/256), dim3(256), 0, stream>>>(geom, wg1,bg1,bng1, wg2,bg2,bng2, h_geom);
  chem_kernel<<<dim3(1048576/64), dim3(256), 0, stream>>>(chem, vids, w1,b1,bn1, w2,b2,bn2, h_chem);
  feat_kernel<<<dim3(V_CNT/32), dim3(256), 0, stream>>>(h_chem, h_geom, wf1,bf1,bnf1, wf2,bf2,bnf2, out);
}

// Round 2
// 1212.478 us; speedup vs baseline: 2.0080x; 2.0080x over previous
//
#include <hip/hip_runtime.h>
#include <cstddef>

constexpr int V_CNT = 65536;
constexpr int H_DIM = 128;
constexpr int CI = 34;   // chem in
constexpr int GI = 48;   // geom in
#define EPSF 1e-5f

typedef _Float16 f16;
typedef f16 f16x8 __attribute__((ext_vector_type(8)));
typedef f16 f16x4 __attribute__((ext_vector_type(4)));
typedef float f32x4 __attribute__((ext_vector_type(4)));
#define MFMA16(a,b,c) __builtin_amdgcn_mfma_f32_16x16x32_f16(a,b,c,0,0,0)

__device__ __forceinline__ float sigmoidf_(float x){ return 1.0f/(1.0f+__expf(-x)); }
__device__ __forceinline__ float siluf_(float x){ return x/(1.0f+__expf(-x)); }
__device__ __forceinline__ float softplusf_(float x){
  return fmaxf(x,0.0f) + __logf(1.0f + __expf(-fabsf(x)));
}
__device__ __forceinline__ void fma4(float4& a, float s, float4 w){
  a.x = fmaf(s,w.x,a.x); a.y = fmaf(s,w.y,a.y);
  a.z = fmaf(s,w.z,a.z); a.w = fmaf(s,w.w,a.w);
}

__global__ __launch_bounds__(256) void zero_f4(float4* p, int n4){
  int i = blockIdx.x*blockDim.x + threadIdx.x;
  int stride = gridDim.x*blockDim.x;
  float4 z; z.x=0.f; z.y=0.f; z.z=0.f; z.w=0.f;
  for(; i<n4; i+=stride) p[i] = z;
}

// ---------------- prep: fold BN scale into weights, convert to f16 (col-major, k contiguous)
// w1f: [128 cols][64 k] (k>=34 zero).  w2f: [256 cols][128 k].
__global__ __launch_bounds__(256) void prep_kernel(
    const float* __restrict__ w1, const float* __restrict__ b1, const float* __restrict__ bn1,
    const float* __restrict__ w2, const float* __restrict__ b2, const float* __restrict__ bn2,
    f16* __restrict__ w1f, float* __restrict__ shift1,
    f16* __restrict__ w2f, float* __restrict__ shift2)
{
  int t = blockIdx.x*256 + threadIdx.x;
  if (t < 128*64){
    int n = t>>6, k = t&63;
    float s = bn1[n]*rsqrtf(bn1[384+n]+EPSF);
    w1f[t] = (k<CI) ? (f16)(w1[k*128+n]*s) : (f16)0.f;
    if (k==0) shift1[n] = fmaf(s, b1[n]-bn1[256+n], bn1[128+n]);
  }
  if (t < 256*128){
    int n = t>>7, k = t&127;
    float s = bn2[n]*rsqrtf(bn2[768+n]+EPSF);
    w2f[t] = (f16)(w2[k*256+n]*s);
    if (k==0) shift2[n] = fmaf(s, b2[n]-bn2[512+n], bn2[256+n]);
  }
}

// ---------------- geom MLP -> h_geom [V,64] stored f16
__global__ __launch_bounds__(256) void geom_kernel(
    const float* __restrict__ geom,
    const float* __restrict__ wg1, const float* __restrict__ bg1, const float* __restrict__ bng1,
    const float* __restrict__ wg2, const float* __restrict__ bg2, const float* __restrict__ bng2,
    f16* __restrict__ h_geom)
{
  __shared__ float w1s[GI][64];
  __shared__ float w2s[64][64];
  __shared__ float sc1[64], sh1[64], sc2[64], sh2[64];
  const int t = threadIdx.x;
  for(int i=t;i<GI*64;i+=256) ((float*)w1s)[i] = wg1[i];
  for(int i=t;i<64*64;i+=256) ((float*)w2s)[i] = wg2[i];
  if(t<64){
    float g=bng1[t], b=bng1[64+t], m=bng1[128+t], vv=bng1[192+t];
    float s=g*rsqrtf(vv+EPSF); sc1[t]=s; sh1[t]=fmaf(s, bg1[t]-m, b);
  } else if(t<128){
    int c=t-64;
    float g=bng2[c], b=bng2[64+c], m=bng2[128+c], vv=bng2[192+c];
    float s=g*rsqrtf(vv+EPSF); sc2[c]=s; sh2[c]=fmaf(s, bg2[c]-m, b);
  }
  __syncthreads();

  const int vtx = blockIdx.x*256 + t;
  float x[GI];
  const float4* xr = (const float4*)(geom + (size_t)vtx*GI);
  #pragma unroll
  for(int i=0;i<GI/4;i++){ float4 q=xr[i]; x[4*i]=q.x; x[4*i+1]=q.y; x[4*i+2]=q.z; x[4*i+3]=q.w; }

  float4 a1[16];
  #pragma unroll
  for(int q=0;q<16;q++){ a1[q].x=0.f; a1[q].y=0.f; a1[q].z=0.f; a1[q].w=0.f; }
  for(int k=0;k<GI;k++){
    float xv = x[k];
    const float4* wr = (const float4*)&w1s[k][0];
    #pragma unroll
    for(int q=0;q<16;q++) fma4(a1[q], xv, wr[q]);
  }
  float g1[64];
  #pragma unroll
  for(int q=0;q<16;q++){
    int j=4*q;
    g1[j+0]=siluf_(fmaf(a1[q].x, sc1[j+0], sh1[j+0]));
    g1[j+1]=siluf_(fmaf(a1[q].y, sc1[j+1], sh1[j+1]));
    g1[j+2]=siluf_(fmaf(a1[q].z, sc1[j+2], sh1[j+2]));
    g1[j+3]=siluf_(fmaf(a1[q].w, sc1[j+3], sh1[j+3]));
  }
  float4 a2[16];
  #pragma unroll
  for(int q=0;q<16;q++){ a2[q].x=0.f; a2[q].y=0.f; a2[q].z=0.f; a2[q].w=0.f; }
  for(int k=0;k<64;k++){
    float gv = g1[k];
    const float4* wr = (const float4*)&w2s[k][0];
    #pragma unroll
    for(int q=0;q<16;q++) fma4(a2[q], gv, wr[q]);
  }
  f16* dst = h_geom + (size_t)vtx*64;
  #pragma unroll
  for(int q=0;q<16;q++){
    int j=4*q;
    f16x4 o;
    o[0]=(f16)fmaf(a2[q].x, sc2[j+0], sh2[j+0]);
    o[1]=(f16)fmaf(a2[q].y, sc2[j+1], sh2[j+1]);
    o[2]=(f16)fmaf(a2[q].z, sc2[j+2], sh2[j+2]);
    o[3]=(f16)fmaf(a2[q].w, sc2[j+3], sh2[j+3]);
    *(f16x4*)(dst+j) = o;
  }
}

// ---------------- chem MLP via MFMA f16 + gated atomic scatter
// 64 edges / block, 256 threads = 4 waves.
// Layer1: C1[64x128] = A1[64x64pad] @ W1f[64x128]; wave w owns n-tiles {2w,2w+1}
// Layer2: C2[64x256] = A2[64x128] @ W2f[128x256]; wave w owns n-tiles {2w,2w+1,2w+8,2w+9}
//   (filter tile t pairs with core tile t+8 within the same wave -> in-register gating)
__global__ __launch_bounds__(256) void chem_mfma(
    const float* __restrict__ chem, const int* __restrict__ vids,
    const f16* __restrict__ w1f, const float* __restrict__ shift1,
    const f16* __restrict__ w2f, const float* __restrict__ shift2,
    float* __restrict__ h_chem)
{
  __shared__ f16 A1[64][72];    // rows 144B: +4-bank stagger, 16B aligned
  __shared__ f16 A2[64][136];   // rows 272B: +4-bank stagger, 16B aligned
  __shared__ __align__(16) int vid_s[64];

  const int t    = threadIdx.x;
  const int w    = t>>6;
  const int lane = t&63;
  const int n16  = lane&15;
  const int quad = lane>>4;
  const long e0  = (long)blockIdx.x*64;

  // --- hoist layer2 B-fragments (global, L2-resident): wave-owned n-tiles
  int ntab[4] = {2*w, 2*w+1, 2*w+8, 2*w+9};
  f16x8 b2[4][4];
  #pragma unroll
  for(int p=0;p<4;p++){
    int col = ntab[p]*16 + n16;
    #pragma unroll
    for(int ks=0;ks<4;ks++)
      b2[p][ks] = *(const f16x8*)(w2f + (size_t)col*128 + ks*32 + quad*8);
  }

  // --- stage A1: zero pad words (k 34..63 => uint words 17..35 of 36/row), fill k<34
  {
    uint* A1w = (uint*)A1;
    for(int i=t;i<64*19;i+=256){ int r=i/19, wd=17+(i-r*19); A1w[r*36+wd] = 0u; }
    for(int i=t;i<64*CI;i+=256){ int e=i/CI, k=i-e*CI; A1[e][k] = (f16)chem[e0*CI + i]; }
    if(t<64) vid_s[t] = vids[e0+t];
  }
  __syncthreads();

  // --- layer1 MFMA
  f16x8 b1[2][2];
  #pragma unroll
  for(int p=0;p<2;p++){
    int col = (2*w+p)*16 + n16;
    #pragma unroll
    for(int ks=0;ks<2;ks++)
      b1[p][ks] = *(const f16x8*)(w1f + (size_t)col*64 + ks*32 + quad*8);
  }
  f32x4 c1[4][2];
  #pragma unroll
  for(int mt=0;mt<4;mt++)
    #pragma unroll
    for(int p=0;p<2;p++) c1[mt][p] = (f32x4)(0.f);
  #pragma unroll
  for(int mt=0;mt<4;mt++){
    #pragma unroll
    for(int ks=0;ks<2;ks++){
      f16x8 a = *(const f16x8*)(&A1[mt*16 + n16][ks*32 + quad*8]);
      #pragma unroll
      for(int p=0;p<2;p++) c1[mt][p] = MFMA16(a, b1[p][ks], c1[mt][p]);
    }
  }
  // activation -> A2 (f16), col j of C1 becomes k=j of layer2 A operand
  float sh1v[2];
  sh1v[0] = shift1[(2*w+0)*16 + n16];
  sh1v[1] = shift1[(2*w+1)*16 + n16];
  #pragma unroll
  for(int mt=0;mt<4;mt++){
    #pragma unroll
    for(int p=0;p<2;p++){
      int col = (2*w+p)*16 + n16;
      #pragma unroll
      for(int r=0;r<4;r++){
        int row = mt*16 + quad*4 + r;
        A2[row][col] = (f16)siluf_(c1[mt][p][r] + sh1v[p]);
      }
    }
  }
  __syncthreads();

  // --- layer2 MFMA
  f32x4 c2[4][4];
  #pragma unroll
  for(int mt=0;mt<4;mt++)
    #pragma unroll
    for(int p=0;p<4;p++) c2[mt][p] = (f32x4)(0.f);
  #pragma unroll
  for(int ks=0;ks<4;ks++){
    f16x8 a[4];
    #pragma unroll
    for(int mt=0;mt<4;mt++)
      a[mt] = *(const f16x8*)(&A2[mt*16 + n16][ks*32 + quad*8]);
    #pragma unroll
    for(int mt=0;mt<4;mt++)
      #pragma unroll
      for(int p=0;p<4;p++)
        c2[mt][p] = MFMA16(a[mt], b2[p][ks], c2[mt][p]);
  }

  // --- gate + scatter
  float shf[2], shc[2];
  shf[0] = shift2[(2*w+0)*16 + n16];
  shf[1] = shift2[(2*w+1)*16 + n16];
  shc[0] = shift2[128 + (2*w+0)*16 + n16];
  shc[1] = shift2[128 + (2*w+1)*16 + n16];
  #pragma unroll
  for(int mt=0;mt<4;mt++){
    int4 ev = *(const int4*)&vid_s[mt*16 + quad*4];
    int evv[4] = {ev.x, ev.y, ev.z, ev.w};
    #pragma unroll
    for(int p=0;p<2;p++){
      int colf = (2*w+p)*16 + n16;
      #pragma unroll
      for(int r=0;r<4;r++){
        float f = sigmoidf_(c2[mt][p][r] + shf[p]);
        float cc = softplusf_(c2[mt][p+2][r] + shc[p]);
        unsafeAtomicAdd(h_chem + (size_t)evv[r]*H_DIM + colf, f*cc);
      }
    }
  }
}

// ---------------- feat MLP: concat(h_chem fp32, h_geom f16) -> out [V,128]
__global__ __launch_bounds__(256) void feat_kernel(
    const float* __restrict__ h_chem, const f16* __restrict__ h_geom,
    const float* __restrict__ wf1, const float* __restrict__ bf1, const float* __restrict__ bnf1,
    const float* __restrict__ wf2, const float* __restrict__ bf2, const float* __restrict__ bnf2,
    float* __restrict__ out)
{
  __shared__ float xsF[32][196];   // padded 192->196
  __shared__ float y1s[32][132];   // padded 128->132
  __shared__ float s1[128], h1[128], s2[128], h2[128];
  const int t = threadIdx.x;
  const int v0 = blockIdx.x*32;

  for(int i=t;i<32*128;i+=256){ int v=i>>7, k=i&127; xsF[v][k]     = h_chem[(size_t)(v0+v)*128 + k]; }
  for(int i=t;i<32*64; i+=256){ int v=i>>6, k=i&63;  xsF[v][128+k] = (float)h_geom[(size_t)(v0+v)*64 + k]; }
  if(t<128){
    float g=bnf1[t], b=bnf1[128+t], m=bnf1[256+t], vv=bnf1[384+t];
    float s=g*rsqrtf(vv+EPSF); s1[t]=s; h1[t]=fmaf(s, bf1[t]-m, b);
  } else {
    int c=t-128;
    float g=bnf2[c], b=bnf2[128+c], m=bnf2[256+c], vv=bnf2[384+c];
    float s=g*rsqrtf(vv+EPSF); s2[c]=s; h2[c]=fmaf(s, bf2[c]-m, b);
  }
  __syncthreads();

  const int v = t>>3, l8 = t&7;
  float4 acc[4];
  #pragma unroll
  for(int q=0;q<4;q++){ acc[q].x=0.f; acc[q].y=0.f; acc[q].z=0.f; acc[q].w=0.f; }
  for(int k=0;k<192;k++){
    float xv = xsF[v][k];
    const float4* wr = (const float4*)(wf1 + (size_t)k*128);
    #pragma unroll
    for(int q=0;q<4;q++) fma4(acc[q], xv, wr[8*q + l8]);
  }
  #pragma unroll
  for(int q=0;q<4;q++){
    int j = 32*q + 4*l8;
    y1s[v][j+0] = siluf_(fmaf(acc[q].x, s1[j+0], h1[j+0]));
    y1s[v][j+1] = siluf_(fmaf(acc[q].y, s1[j+1], h1[j+1]));
    y1s[v][j+2] = siluf_(fmaf(acc[q].z, s1[j+2], h1[j+2]));
    y1s[v][j+3] = siluf_(fmaf(acc[q].w, s1[j+3], h1[j+3]));
  }
  __syncthreads();

  float4 acc2[4];
  #pragma unroll
  for(int q=0;q<4;q++){ acc2[q].x=0.f; acc2[q].y=0.f; acc2[q].z=0.f; acc2[q].w=0.f; }
  for(int k=0;k<128;k++){
    float yv = y1s[v][k];
    const float4* wr = (const float4*)(wf2 + (size_t)k*128);
    #pragma unroll
    for(int q=0;q<4;q++) fma4(acc2[q], yv, wr[8*q + l8]);
  }
  #pragma unroll
  for(int q=0;q<4;q++){
    int j = 32*q + 4*l8;
    float4 o;
    o.x=fmaf(acc2[q].x, s2[j+0], h2[j+0]);
    o.y=fmaf(acc2[q].y, s2[j+1], h2[j+1]);
    o.z=fmaf(acc2[q].z, s2[j+2], h2[j+2]);
    o.w=fmaf(acc2[q].w, s2[j+3], h2[j+3]);
    *(float4*)(out + (size_t)(v0+v)*128 + j) = o;
  }
}

extern "C" void kernel_launch(void* const* d_in, const int* in_sizes, int n_in,
                              void* d_out, int out_size, void* d_ws, size_t ws_size,
                              hipStream_t stream) {
  const float* chem = (const float*)d_in[0];
  const float* geom = (const float*)d_in[1];
  const int*   vids = (const int*)d_in[2];
  const float* w1  = (const float*)d_in[3];
  const float* b1  = (const float*)d_in[4];
  const float* bn1 = (const float*)d_in[5];
  const float* w2  = (const float*)d_in[6];
  const float* b2  = (const float*)d_in[7];
  const float* bn2 = (const float*)d_in[8];
  const float* wg1 = (const float*)d_in[9];
  const float* bg1 = (const float*)d_in[10];
  const float* bng1= (const float*)d_in[11];
  const float* wg2 = (const float*)d_in[12];
  const float* bg2 = (const float*)d_in[13];
  const float* bng2= (const float*)d_in[14];
  const float* wf1 = (const float*)d_in[15];
  const float* bf1 = (const float*)d_in[16];
  const float* bnf1= (const float*)d_in[17];
  const float* wf2 = (const float*)d_in[18];
  const float* bf2 = (const float*)d_in[19];
  const float* bnf2= (const float*)d_in[20];

  char* ws = (char*)d_ws;
  float* h_chem = (float*)ws;                              // 32 MB
  f16*   h_geom = (f16*)(ws + 33554432);                   // 8 MB
  f16*   w1f    = (f16*)(ws + 41943040);                   // 16 KB
  f16*   w2f    = (f16*)(ws + 41943040 + 16384);           // 64 KB
  float* shift1 = (float*)(ws + 41943040 + 16384 + 65536); // 512 B
  float* shift2 = (float*)(ws + 41943040 + 16384 + 65536 + 512); // 1 KB
  float* out    = (float*)d_out;

  prep_kernel<<<dim3(128), dim3(256), 0, stream>>>(w1,b1,bn1, w2,b2,bn2, w1f,shift1, w2f,shift2);
  zero_f4<<<dim3(4096), dim3(256), 0, stream>>>((float4*)h_chem, V_CNT*H_DIM/4);
  geom_kernel<<<dim3(V_CNT/256), dim3(256), 0, stream>>>(geom, wg1,bg1,bng1, wg2,bg2,bng2, h_geom);
  chem_mfma<<<dim3(1048576/64), dim3(256), 0, stream>>>(chem, vids, w1f,shift1, w2f,shift2, h_chem);
  feat_kernel<<<dim3(V_CNT/32), dim3(256), 0, stream>>>(h_chem, h_geom, wf1,bf1,bnf1, wf2,bf2,bnf2, out);
}